// Round 13
// baseline (48.736 us; speedup 1.0000x reference)
//
#include <hip/hip_runtime.h>
#include <stdint.h>

// Problem constants
#define CHELEM 131072        // 2048*64 elements per chunk (flat-reshape chunk)

typedef __attribute__((ext_vector_type(4))) float   f32x4;
typedef __attribute__((ext_vector_type(8))) short   bh8;     // 8 bf16 in 4 VGPRs
typedef __attribute__((ext_vector_type(4))) unsigned short u16x4;
typedef __attribute__((ext_vector_type(8))) unsigned short u16x8;
typedef unsigned short u16;

__device__ inline u16 f2bf(float f) {
    union { float f; uint32_t u; } v; v.f = f;
    uint32_t u = v.u;
    u += 0x7FFF + ((u >> 16) & 1);         // RNE
    return (u16)(u >> 16);
}

__device__ inline void gload_lds16(const u16* g, u16* l) {
    __builtin_amdgcn_global_load_lds(
        (const __attribute__((address_space(1))) uint32_t*)g,
        (__attribute__((address_space(3)))       uint32_t*)l,
        16, 0, 0);
}

// ---------------- K0: convert x, Wq, Wk, Wv to bf16 (verbatim R8) ----------------
__global__ __launch_bounds__(256) void k0_convert(
        const float* __restrict__ x,
        const float* __restrict__ Wq,
        const float* __restrict__ Wk,
        const float* __restrict__ Wv,
        u16* __restrict__ xb, u16* __restrict__ Wb) {
    int idx = blockIdx.x * 256 + threadIdx.x;   // float4 index, 720896 total
    const float4* src; u16* dst; int off;
    if (idx < 524288) { src = (const float4*)x; dst = xb; off = idx; }
    else {
        int j = idx - 524288;
        int w = j >> 16;                        // 65536 float4 per W
        off = j & 65535;
        src = (const float4*)(w == 0 ? Wq : (w == 1 ? Wk : Wv));
        dst = Wb + w * 262144;
    }
    float4 f = src[off];
    u16x4 o;
    o[0] = f2bf(f.x); o[1] = f2bf(f.y); o[2] = f2bf(f.z); o[3] = f2bf(f.w);
    *(u16x4*)(dst + off * 4) = o;
}

// ---------------- K1: QKV projection GEMM ----------------
// R8 structure (verified 2-phase: stage -> vmcnt(0)+__syncthreads -> MFMA),
// ONE parameter change: BK 64 -> 128 (4 K-steps instead of 8; halves the
// per-iteration barrier+latency stalls; LDS 48KB keeps 3 blocks/CU).
// Q (w==0): straight [4096][512]. K,V: TRANSPOSED per chunk Kt2[c][d][g][q]
// (c=m>>8, d=f&63, g=f>>6, q=m&255; row r=q*8+g bijection, same perm for K,V).
__global__ __launch_bounds__(256) void k1_qkv(
        const u16* __restrict__ xb, const u16* __restrict__ Wb,
        const float* __restrict__ bq, const float* __restrict__ bk,
        const float* __restrict__ bv,
        u16* __restrict__ Qb, u16* __restrict__ Kb, u16* __restrict__ Vb) {
    __shared__ u16 smem[24576];                 // lA[64][128] + lB[128][128]; epi tile[64][130] aliases
    u16* lA = smem;                             // 16 KB
    u16* lB = smem + 8192;                      // 32 KB
    const int tid  = threadIdx.x;
    const int lane = tid & 63, wid = tid >> 6;
    const int wr = wid >> 1, wc = wid & 1;      // wave owns 32 rows x 64 cols
    const int swz  = (blockIdx.x & 7) * 96 + (blockIdx.x >> 3);   // XCD swizzle
    const int mb = swz / 12, nb = swz % 12;
    const int w    = nb >> 2;
    const int nloc = (nb & 3) * 128;
    const u16*   W    = Wb + w * 262144;
    const float* bias = (w == 0) ? bq : ((w == 1) ? bk : bv);
    u16*         out  = (w == 0) ? Qb : ((w == 1) ? Kb : Vb);
    const int m0 = mb * 64;

    f32x4 acc[2][4] = {};
    const int srow = tid >> 4;                  // 0..15
    const int scol = (tid & 15) * 8;            // 0..120

    for (int kb = 0; kb < 4; ++kb) {
        __syncthreads();
        const int k0 = kb * 128;
#pragma unroll
        for (int it = 0; it < 4; ++it) {        // A: 64 rows x 128 cols
            int r = it * 16 + srow;
            gload_lds16(xb + (size_t)(m0 + r) * 512 + k0 + scol, lA + r * 128 + scol);
        }
#pragma unroll
        for (int it = 0; it < 8; ++it) {        // B: 128 rows x 128 cols
            int r = it * 16 + srow;
            gload_lds16(W + (size_t)(nloc + r) * 512 + k0 + scol, lB + r * 128 + scol);
        }
        asm volatile("s_waitcnt vmcnt(0)" ::: "memory");
        __syncthreads();
#pragma unroll
        for (int ks = 0; ks < 4; ++ks) {
            const int kk = ks * 32 + (lane >> 4) * 8;
            bh8 a[2], b[4];
#pragma unroll
            for (int i = 0; i < 2; ++i)
                a[i] = *(const bh8*)&lA[(wr * 32 + i * 16 + (lane & 15)) * 128 + kk];
#pragma unroll
            for (int j = 0; j < 4; ++j)
                b[j] = *(const bh8*)&lB[(wc * 64 + j * 16 + (lane & 15)) * 128 + kk];
#pragma unroll
            for (int i = 0; i < 2; ++i)
#pragma unroll
                for (int j = 0; j < 4; ++j)
                    acc[i][j] = __builtin_amdgcn_mfma_f32_16x16x32_bf16(a[i], b[j], acc[i][j], 0, 0, 0);
        }
    }

    if (w == 0) {
        // straight store (Q)
#pragma unroll
        for (int i = 0; i < 2; ++i) {
            const int row_base = m0 + wr * 32 + i * 16 + ((lane >> 4) * 4);
#pragma unroll
            for (int j = 0; j < 4; ++j) {
                const int col = nloc + wc * 64 + j * 16 + (lane & 15);
                const float bv_ = bias[col];
#pragma unroll
                for (int r = 0; r < 4; ++r)
                    out[(size_t)(row_base + r) * 512 + col] = f2bf(acc[i][j][r] + bv_);
            }
        }
    } else {
        // transposed store (K,V): stage to padded LDS tile, scatter to Kt2[c][d][g][q]
        __syncthreads();                        // main-loop LDS reads done
        u16 (*tile)[130] = (u16(*)[130])smem;
#pragma unroll
        for (int i = 0; i < 2; ++i) {
            const int ml = wr * 32 + i * 16 + ((lane >> 4) * 4);
#pragma unroll
            for (int j = 0; j < 4; ++j) {
                const int nl = wc * 64 + j * 16 + (lane & 15);
                const float bv_ = bias[nloc + nl];
#pragma unroll
                for (int r = 0; r < 4; ++r)
                    tile[ml + r][nl] = f2bf(acc[i][j][r] + bv_);
            }
        }
        __syncthreads();
        const int ncol  = tid & 127;
        const int mhalf = tid >> 7;
        const int g = (nb & 3) * 2 + (ncol >> 6);
        const int d = ncol & 63;
        const int c = mb >> 2;
        const int qbase = (mb & 3) * 64 + mhalf * 32;
        u16* dst = out + (size_t)c * CHELEM + d * 2048 + g * 256 + qbase;
#pragma unroll
        for (int v = 0; v < 4; ++v) {
            u16x8 t;
#pragma unroll
            for (int j = 0; j < 8; ++j)
                t[j] = tile[mhalf * 32 + v * 8 + j][ncol];
            *(u16x8*)(dst + v * 8) = t;
        }
    }
}

// ---------------- K2: Pb[c][d][e] = scale * sum_k Vt2[c][d][k] * Kt2[c][e][k] ----------------
// (verbatim R8 winner) 256 blocks: c = bid%16, sub = bid/16 -> 16x16 (d,e)
// subtile. 4 waves split K=2048; frags direct from global; LDS reduce.
__global__ __launch_bounds__(256) void k2_pmat(
        const u16* __restrict__ Kt2, const u16* __restrict__ Vt2,
        u16* __restrict__ Pb) {
    __shared__ float red[4][16][16];
    const int tid = threadIdx.x;
    const int lane = tid & 63, w = tid >> 6;
    const int c   = blockIdx.x & 15;
    const int sub = blockIdx.x >> 4;
    const int dq = sub >> 2, eq = sub & 3;
    const u16* Vc = Vt2 + (size_t)c * CHELEM;
    const u16* Kc = Kt2 + (size_t)c * CHELEM;
    const int krow = lane & 15;
    const int arow = (dq * 16 + krow) * 2048;
    const int brow = (eq * 16 + krow) * 2048;
    const int kb = w * 512 + (lane >> 4) * 8;

    f32x4 acc = {};
#pragma unroll
    for (int kt = 0; kt < 16; ++kt) {
        const int k0 = kb + kt * 32;
        bh8 a = *(const bh8*)&Vc[arow + k0];
        bh8 b = *(const bh8*)&Kc[brow + k0];
        acc = __builtin_amdgcn_mfma_f32_16x16x32_bf16(a, b, acc, 0, 0, 0);
    }
#pragma unroll
    for (int r = 0; r < 4; ++r)
        red[w][(lane >> 4) * 4 + r][lane & 15] = acc[r];
    __syncthreads();
    const int row = tid >> 4, col = tid & 15;
    float s = red[0][row][col] + red[1][row][col] + red[2][row][col] + red[3][row][col];
    Pb[c * 4096 + (dq * 16 + row) * 64 + eq * 16 + col] = f2bf(s * 0.125f);  // scale = DIM^-0.5
}

// ---------------- K3: out_c = Q_c @ P_c^T  (K=64 per head, no LDS; verbatim R8) ----------------
__global__ __launch_bounds__(256) void k3_out(
        const u16* __restrict__ Qb, const u16* __restrict__ Pb,
        float* __restrict__ outp) {
    const int tid = threadIdx.x;
    const int lane = tid & 63, w = tid >> 6;
    const int bb = blockIdx.x >> 6;          // 128 blocks: 64 row-blocks per bb
    const int ib = blockIdx.x & 63;
    const int i0 = ib * 32 + (w >> 1) * 16;
    const int dbase = (w & 1) * 32;
    const int krow = lane & 15;
    const int koff = (lane >> 4) * 8;

    f32x4 acc[8][2] = {};                    // [head][nf]
#pragma unroll
    for (int h = 0; h < 8; ++h) {
        const int c = h * 2 + bb;
        const u16* Qc = Qb + (size_t)c * CHELEM;
        const u16* Pc = Pb + c * 4096;
#pragma unroll
        for (int ks = 0; ks < 2; ++ks) {
            bh8 a = *(const bh8*)&Qc[(i0 + krow) * 64 + ks * 32 + koff];
#pragma unroll
            for (int nf = 0; nf < 2; ++nf) {
                bh8 b = *(const bh8*)&Pc[(dbase + nf * 16 + krow) * 64 + ks * 32 + koff];
                acc[h][nf] = __builtin_amdgcn_mfma_f32_16x16x32_bf16(a, b, acc[h][nf], 0, 0, 0);
            }
        }
    }
    const int orow_base = bb * 2048 + ib * 32 + (w >> 1) * 16 + (lane >> 4) * 4;
#pragma unroll
    for (int nf = 0; nf < 2; ++nf) {
        const int d = dbase + nf * 16 + (lane & 15);
#pragma unroll
        for (int r = 0; r < 4; ++r) {
            f32x4 lo = {acc[0][nf][r], acc[1][nf][r], acc[2][nf][r], acc[3][nf][r]};
            f32x4 hi = {acc[4][nf][r], acc[5][nf][r], acc[6][nf][r], acc[7][nf][r]};
            float* dst = outp + (size_t)(orow_base + r) * 512 + d * 8;
            *(f32x4*)dst = lo;
            *(f32x4*)(dst + 4) = hi;
        }
    }
}

extern "C" void kernel_launch(void* const* d_in, const int* in_sizes, int n_in,
                              void* d_out, int out_size, void* d_ws, size_t ws_size,
                              hipStream_t stream) {
    const float* x  = (const float*)d_in[0];
    const float* Wq = (const float*)d_in[1];
    const float* bq = (const float*)d_in[2];
    const float* Wk = (const float*)d_in[3];
    const float* bk = (const float*)d_in[4];
    const float* Wv = (const float*)d_in[5];
    const float* bv = (const float*)d_in[6];
    float* outp = (float*)d_out;

    u16* xb = (u16*)d_ws;                 // 4096*512
    u16* Wb = xb + 2097152;               // 3*512*512
    u16* Qb = Wb + 786432;                // 4096*512 (straight)
    u16* Kb = Qb + 2097152;               // Kt2 transposed chunks
    u16* Vb = Kb + 2097152;               // Vt2 transposed chunks
    u16* Pb = Vb + 2097152;               // 16*64*64

    k0_convert<<<2816, 256, 0, stream>>>(x, Wq, Wk, Wv, xb, Wb);
    k1_qkv<<<768, 256, 0, stream>>>(xb, Wb, bq, bk, bv, Qb, Kb, Vb);
    k2_pmat<<<256, 256, 0, stream>>>(Kb, Vb, Pb);
    k3_out<<<128, 256, 0, stream>>>(Qb, Pb, outp);
}

// Round 14
// 39.093 us; speedup vs baseline: 1.2467x; 1.2467x over previous
//
#include <hip/hip_runtime.h>
#include <stdint.h>

// Problem constants
#define CHELEM 131072        // 2048*64 elements per chunk (flat-reshape chunk)

typedef __attribute__((ext_vector_type(4))) float   f32x4;
typedef __attribute__((ext_vector_type(8))) short   bh8;     // 8 bf16 in 4 VGPRs
typedef __attribute__((ext_vector_type(4))) unsigned short u16x4;
typedef __attribute__((ext_vector_type(8))) unsigned short u16x8;
typedef unsigned short u16;

__device__ inline u16 f2bf(float f) {
    union { float f; uint32_t u; } v; v.f = f;
    uint32_t u = v.u;
    u += 0x7FFF + ((u >> 16) & 1);         // RNE
    return (u16)(u >> 16);
}

__device__ inline void gload_lds16(const u16* g, u16* l) {
    __builtin_amdgcn_global_load_lds(
        (const __attribute__((address_space(1))) uint32_t*)g,
        (__attribute__((address_space(3)))       uint32_t*)l,
        16, 0, 0);
}

// ---------------- K0: convert x, Wq, Wk, Wv to bf16 (verbatim R8) ----------------
__global__ __launch_bounds__(256) void k0_convert(
        const float* __restrict__ x,
        const float* __restrict__ Wq,
        const float* __restrict__ Wk,
        const float* __restrict__ Wv,
        u16* __restrict__ xb, u16* __restrict__ Wb) {
    int idx = blockIdx.x * 256 + threadIdx.x;   // float4 index, 720896 total
    const float4* src; u16* dst; int off;
    if (idx < 524288) { src = (const float4*)x; dst = xb; off = idx; }
    else {
        int j = idx - 524288;
        int w = j >> 16;                        // 65536 float4 per W
        off = j & 65535;
        src = (const float4*)(w == 0 ? Wq : (w == 1 ? Wk : Wv));
        dst = Wb + w * 262144;
    }
    float4 f = src[off];
    u16x4 o;
    o[0] = f2bf(f.x); o[1] = f2bf(f.y); o[2] = f2bf(f.z); o[3] = f2bf(f.w);
    *(u16x4*)(dst + off * 4) = o;
}

// ---------------- K1: QKV projection GEMM (verbatim R8 winner: 64x128, BK=64) ----------------
// C[m,n] = sum_k xb[m,k]*W[n,k] + bias[n]  (gemm_bt), 768 blocks = 3/CU.
// Q (w==0): straight [4096][512]. K,V: TRANSPOSED per chunk Kt2[c][d][g][q]
// (c=m>>8, d=f&63, g=f>>6, q=m&255; row r=q*8+g bijection, same perm for K,V).
__global__ __launch_bounds__(256) void k1_qkv(
        const u16* __restrict__ xb, const u16* __restrict__ Wb,
        const float* __restrict__ bq, const float* __restrict__ bk,
        const float* __restrict__ bv,
        u16* __restrict__ Qb, u16* __restrict__ Kb, u16* __restrict__ Vb) {
    __shared__ u16 smem[12288];                 // lA[4096]+lB[8192]; epi tile[64][130] aliases
    u16* lA = smem;
    u16* lB = smem + 4096;
    const int tid  = threadIdx.x;
    const int lane = tid & 63, wid = tid >> 6;
    const int wr = wid >> 1, wc = wid & 1;
    const int swz  = (blockIdx.x & 7) * 96 + (blockIdx.x >> 3);   // XCD swizzle
    const int mb = swz / 12, nb = swz % 12;
    const int w    = nb >> 2;
    const int nloc = (nb & 3) * 128;
    const u16*   W    = Wb + w * 262144;
    const float* bias = (w == 0) ? bq : ((w == 1) ? bk : bv);
    u16*         out  = (w == 0) ? Qb : ((w == 1) ? Kb : Vb);
    const int m0 = mb * 64;

    f32x4 acc[2][4] = {};
    const int srow = tid >> 3;
    const int scol = (tid & 7) * 8;

    for (int kb = 0; kb < 8; ++kb) {
        __syncthreads();
        const int k0 = kb * 64;
#pragma unroll
        for (int it = 0; it < 2; ++it) {
            int r = it * 32 + srow;
            gload_lds16(xb + (size_t)(m0 + r) * 512 + k0 + scol, lA + r * 64 + scol);
        }
#pragma unroll
        for (int it = 0; it < 4; ++it) {
            int r = it * 32 + srow;
            gload_lds16(W + (size_t)(nloc + r) * 512 + k0 + scol, lB + r * 64 + scol);
        }
        asm volatile("s_waitcnt vmcnt(0)" ::: "memory");
        __syncthreads();
#pragma unroll
        for (int ks = 0; ks < 2; ++ks) {
            const int kk = ks * 32 + (lane >> 4) * 8;
            bh8 a[2], b[4];
#pragma unroll
            for (int i = 0; i < 2; ++i)
                a[i] = *(const bh8*)&lA[(wr * 32 + i * 16 + (lane & 15)) * 64 + kk];
#pragma unroll
            for (int j = 0; j < 4; ++j)
                b[j] = *(const bh8*)&lB[(wc * 64 + j * 16 + (lane & 15)) * 64 + kk];
#pragma unroll
            for (int i = 0; i < 2; ++i)
#pragma unroll
                for (int j = 0; j < 4; ++j)
                    acc[i][j] = __builtin_amdgcn_mfma_f32_16x16x32_bf16(a[i], b[j], acc[i][j], 0, 0, 0);
        }
    }

    if (w == 0) {
        // straight store (Q)
#pragma unroll
        for (int i = 0; i < 2; ++i) {
            const int row_base = m0 + wr * 32 + i * 16 + ((lane >> 4) * 4);
#pragma unroll
            for (int j = 0; j < 4; ++j) {
                const int col = nloc + wc * 64 + j * 16 + (lane & 15);
                const float bv_ = bias[col];
#pragma unroll
                for (int r = 0; r < 4; ++r)
                    out[(size_t)(row_base + r) * 512 + col] = f2bf(acc[i][j][r] + bv_);
            }
        }
    } else {
        // transposed store (K,V): stage to padded LDS tile, scatter to Kt2[c][d][g][q]
        __syncthreads();
        u16 (*tile)[130] = (u16(*)[130])smem;
#pragma unroll
        for (int i = 0; i < 2; ++i) {
            const int ml = wr * 32 + i * 16 + ((lane >> 4) * 4);
#pragma unroll
            for (int j = 0; j < 4; ++j) {
                const int nl = wc * 64 + j * 16 + (lane & 15);
                const float bv_ = bias[nloc + nl];
#pragma unroll
                for (int r = 0; r < 4; ++r)
                    tile[ml + r][nl] = f2bf(acc[i][j][r] + bv_);
            }
        }
        __syncthreads();
        const int ncol  = tid & 127;
        const int mhalf = tid >> 7;
        const int g = (nb & 3) * 2 + (ncol >> 6);
        const int d = ncol & 63;
        const int c = mb >> 2;
        const int qbase = (mb & 3) * 64 + mhalf * 32;
        u16* dst = out + (size_t)c * CHELEM + d * 2048 + g * 256 + qbase;
#pragma unroll
        for (int v = 0; v < 4; ++v) {
            u16x8 t;
#pragma unroll
            for (int j = 0; j < 8; ++j)
                t[j] = tile[mhalf * 32 + v * 8 + j][ncol];
            *(u16x8*)(dst + v * 8) = t;
        }
    }
}

// ---------------- K2: Pb[c][d][e] = scale * sum_k Vt2[c][d][k] * Kt2[c][e][k] ----------------
// (verbatim R8 winner) 256 blocks: c = bid%16, sub = bid/16 -> 16x16 (d,e)
// subtile. 4 waves split K=2048; frags direct from global; LDS reduce.
__global__ __launch_bounds__(256) void k2_pmat(
        const u16* __restrict__ Kt2, const u16* __restrict__ Vt2,
        u16* __restrict__ Pb) {
    __shared__ float red[4][16][16];
    const int tid = threadIdx.x;
    const int lane = tid & 63, w = tid >> 6;
    const int c   = blockIdx.x & 15;
    const int sub = blockIdx.x >> 4;
    const int dq = sub >> 2, eq = sub & 3;
    const u16* Vc = Vt2 + (size_t)c * CHELEM;
    const u16* Kc = Kt2 + (size_t)c * CHELEM;
    const int krow = lane & 15;
    const int arow = (dq * 16 + krow) * 2048;
    const int brow = (eq * 16 + krow) * 2048;
    const int kb = w * 512 + (lane >> 4) * 8;

    f32x4 acc = {};
#pragma unroll
    for (int kt = 0; kt < 16; ++kt) {
        const int k0 = kb + kt * 32;
        bh8 a = *(const bh8*)&Vc[arow + k0];
        bh8 b = *(const bh8*)&Kc[brow + k0];
        acc = __builtin_amdgcn_mfma_f32_16x16x32_bf16(a, b, acc, 0, 0, 0);
    }
#pragma unroll
    for (int r = 0; r < 4; ++r)
        red[w][(lane >> 4) * 4 + r][lane & 15] = acc[r];
    __syncthreads();
    const int row = tid >> 4, col = tid & 15;
    float s = red[0][row][col] + red[1][row][col] + red[2][row][col] + red[3][row][col];
    Pb[c * 4096 + (dq * 16 + row) * 64 + eq * 16 + col] = f2bf(s * 0.125f);  // scale = DIM^-0.5
}

// ---------------- K3: out_c = Q_c @ P_c^T  (K=64 per head, no LDS) ----------------
// 256 blocks (R10-verified consumer geometry): block = 16 rows x 512 cols of
// one batch; wave w owns d-group [w*16, w*16+16). 1 block/CU -> full chip.
__global__ __launch_bounds__(256) void k3_out(
        const u16* __restrict__ Qb, const u16* __restrict__ Pb,
        float* __restrict__ outp) {
    const int tid = threadIdx.x;
    const int lane = tid & 63, w = tid >> 6;
    const int bid = blockIdx.x;
    const int bb = bid >> 7;                 // batch
    const int ib = bid & 127;                // 128 row-blocks of 16 per batch
    const int i0 = ib * 16;
    const int dbase = w * 16;                // wave owns one 16-wide d-group
    const int krow = lane & 15;
    const int koff = (lane >> 4) * 8;

    f32x4 acc[8] = {};                       // [head]
#pragma unroll
    for (int h = 0; h < 8; ++h) {
        const int c = h * 2 + bb;
        const u16* Qc = Qb + (size_t)c * CHELEM;
        const u16* Pc = Pb + c * 4096;
#pragma unroll
        for (int ks = 0; ks < 2; ++ks) {
            bh8 a = *(const bh8*)&Qc[(i0 + krow) * 64 + ks * 32 + koff];
            bh8 b = *(const bh8*)&Pc[(dbase + krow) * 64 + ks * 32 + koff];
            acc[h] = __builtin_amdgcn_mfma_f32_16x16x32_bf16(a, b, acc[h], 0, 0, 0);
        }
    }
    const int orow_base = bb * 2048 + i0 + (lane >> 4) * 4;
    const int d = dbase + (lane & 15);
#pragma unroll
    for (int r = 0; r < 4; ++r) {
        f32x4 lo = {acc[0][r], acc[1][r], acc[2][r], acc[3][r]};
        f32x4 hi = {acc[4][r], acc[5][r], acc[6][r], acc[7][r]};
        float* dst = outp + (size_t)(orow_base + r) * 512 + d * 8;
        *(f32x4*)dst = lo;
        *(f32x4*)(dst + 4) = hi;
    }
}

extern "C" void kernel_launch(void* const* d_in, const int* in_sizes, int n_in,
                              void* d_out, int out_size, void* d_ws, size_t ws_size,
                              hipStream_t stream) {
    const float* x  = (const float*)d_in[0];
    const float* Wq = (const float*)d_in[1];
    const float* bq = (const float*)d_in[2];
    const float* Wk = (const float*)d_in[3];
    const float* bk = (const float*)d_in[4];
    const float* Wv = (const float*)d_in[5];
    const float* bv = (const float*)d_in[6];
    float* outp = (float*)d_out;

    u16* xb = (u16*)d_ws;                 // 4096*512
    u16* Wb = xb + 2097152;               // 3*512*512
    u16* Qb = Wb + 786432;                // 4096*512 (straight)
    u16* Kb = Qb + 2097152;               // Kt2 transposed chunks
    u16* Vb = Kb + 2097152;               // Vt2 transposed chunks
    u16* Pb = Vb + 2097152;               // 16*64*64

    k0_convert<<<2816, 256, 0, stream>>>(x, Wq, Wk, Wv, xb, Wb);
    k1_qkv<<<768, 256, 0, stream>>>(xb, Wb, bq, bk, bv, Qb, Kb, Vb);
    k2_pmat<<<256, 256, 0, stream>>>(Kb, Vb, Pb);
    k3_out<<<256, 256, 0, stream>>>(Qb, Pb, outp);
}